// Round 10
// baseline (185.296 us; speedup 1.0000x reference)
//
#include <hip/hip_runtime.h>

#define V3 (128 * 128 * 128)   // 2097152 voxels per volume

typedef _Float16 h8 __attribute__((ext_vector_type(8)));
typedef float    f8 __attribute__((ext_vector_type(8)));

// ---------------- block reduction (wave64) ----------------
__device__ __forceinline__ float block_reduce(float v, float* sm) {
#pragma unroll
  for (int off = 32; off > 0; off >>= 1) v += __shfl_down(v, off, 64);
  int lane = threadIdx.x & 63;
  int wid  = threadIdx.x >> 6;
  if (lane == 0) sm[wid] = v;
  __syncthreads();
  float r = 0.f;
  if ((int)threadIdx.x < (int)(blockDim.x >> 6)) r = sm[threadIdx.x];
  if (wid == 0) {
#pragma unroll
    for (int off = 4; off > 0; off >>= 1) r += __shfl_down(r, off, 64);
  }
  __syncthreads();
  return r;  // valid on thread 0
}

// masked fp16x8 load -> f32x8
__device__ __forceinline__ f8 ldh(const _Float16* __restrict__ p, size_t off,
                                  float m) {
  h8 q = *(const h8*)(p + off);
  f8 r = __builtin_convertvector(q, f8);
  return r * m;
}

// ---------------- pred_mask area sums (per t), float4 ----------------
__global__ __launch_bounds__(256) void area_kernel(const float* __restrict__ pm,
                                                   float* __restrict__ acc) {
  __shared__ float sm[8];
  const int t = blockIdx.y;
  const float* p = pm + (size_t)t * V3;
  const int n4 = V3 / 4;
  float s = 0.f;
  for (int i = blockIdx.x * blockDim.x + threadIdx.x; i < n4;
       i += gridDim.x * blockDim.x) {
    float4 a = *(const float4*)(p + 4 * (size_t)i);
    s += (a.x + a.y) + (a.z + a.w);
  }
  s = block_reduce(s, sm);
  if (threadIdx.x == 0) atomicAdd(acc + t, s);
}

// ---------------- flow gradient: 9 independent loads per 4 outputs -----------
// Block = 256 = 8 h-rows x 32 w4. Grid = (16 h-tiles, 32 d-groups of 4, 9 c).
__global__ __launch_bounds__(256) void grad_kernel(const float* __restrict__ fl,
                                                   float* __restrict__ acc) {
  __shared__ float sm[8];
  const int w4 = threadIdx.x & 31;
  const int hl = threadIdx.x >> 5;
  const int h  = blockIdx.x * 8 + hl;
  const int d0 = blockIdx.y * 4;
  const int c  = blockIdx.z;
  const float* p = fl + (size_t)c * V3 + (size_t)h * 128 + w4 * 4;
  const bool hv = (h < 127);

  float4 self[5];
  float4 hn[4];
#pragma unroll
  for (int j = 0; j < 5; ++j) {
    const int d  = d0 + j;
    const int dc = (d < 128) ? d : 127;   // only j=4 can overflow
    self[j] = *(const float4*)(p + (size_t)dc * 16384);
  }
#pragma unroll
  for (int j = 0; j < 4; ++j) {
    hn[j] = hv ? *(const float4*)(p + (size_t)(d0 + j) * 16384 + 128) : self[j];
  }

  float s = 0.f;
#pragma unroll
  for (int j = 0; j < 4; ++j) {
    const float4 a = self[j];
    float x;
    x = a.y - a.x; s += x * x;
    x = a.z - a.y; s += x * x;
    x = a.w - a.z; s += x * x;
    const float nx = __shfl_down(a.x, 1, 64);
    if (w4 != 31) { x = nx - a.w; s += x * x; }
    if (hv) {
      const float4 b = hn[j];
      x = b.x - a.x; s += x * x;
      x = b.y - a.y; s += x * x;
      x = b.z - a.z; s += x * x;
      x = b.w - a.w; s += x * x;
    }
    if ((d0 + j) < 127) {
      const float4 bd = self[j + 1];
      x = bd.x - a.x; s += x * x;
      x = bd.y - a.y; s += x * x;
      x = bd.z - a.z; s += x * x;
      x = bd.w - a.w; s += x * x;
    }
  }
  s = block_reduce(s, sm);
  if (threadIdx.x == 0) atomicAdd(acc, s);
}

// ---------------- NCC pass 1: W+H box sums -> fp16 planes (r6 version) -------
// Block = 256 = 2 d-slices x 128 w. Grid = (8 h-chunks of 16, 64 d-pairs, NT).
template <bool WITH_I>
__global__ __launch_bounds__(256) void n1_kernel(const float* __restrict__ I0,
                                                 const float* __restrict__ Jall,
                                                 _Float16* __restrict__ FI,
                                                 _Float16* __restrict__ FJall) {
  constexpr int NF = WITH_I ? 5 : 3;
  __shared__ float sI[2][2][136];
  __shared__ float sJ[2][2][136];
  __shared__ float ring[2][9][NF][128];

  const int tz = blockIdx.z;
  const float* J = Jall + (size_t)tz * V3;
  _Float16* FJ = FJall + (size_t)tz * 3 * (size_t)V3;

  const int w  = threadIdx.x & 127;
  const int dl = threadIdx.x >> 7;
  const int d  = blockIdx.y * 2 + dl;
  const int h0 = blockIdx.x * 16;
  const float* Ib = I0 + (size_t)d * 16384;
  const float* Jb = J  + (size_t)d * 16384;

  if (w < 4) {
    sI[dl][0][w] = 0.f; sI[dl][1][w] = 0.f;
    sJ[dl][0][w] = 0.f; sJ[dl][1][w] = 0.f;
  }
  if (w >= 124) {
    sI[dl][0][w + 8] = 0.f; sI[dl][1][w + 8] = 0.f;
    sJ[dl][0][w + 8] = 0.f; sJ[dl][1][w + 8] = 0.f;
  }
#pragma unroll
  for (int sl = 0; sl < 9; ++sl)
#pragma unroll
    for (int f = 0; f < NF; ++f) ring[dl][sl][f][w] = 0.f;

  auto stage = [&](int hh) {
    if (hh >= 0 && hh < 128) {
      const int b = hh & 1;
      if (w < 32) {
        float4 v = *(const float4*)(Ib + hh * 128 + w * 4);
        *(float4*)&sI[dl][b][4 + w * 4] = v;
      } else if (w < 64) {
        const int l = w - 32;
        float4 v = *(const float4*)(Jb + hh * 128 + l * 4);
        *(float4*)&sJ[dl][b][4 + l * 4] = v;
      }
    }
  };

  float S[NF];
#pragma unroll
  for (int f = 0; f < NF; ++f) S[f] = 0.f;

  stage(h0 - 4);
  int slot = (h0 + 32) % 9;

  for (int hh = h0 - 4; hh < h0 + 20; ++hh) {
    __syncthreads();
    stage(hh + 1);
    const int b = hh & 1;
    const bool valid = (hh >= 0) && (hh < 128);

    float Wn[NF];
#pragma unroll
    for (int f = 0; f < NF; ++f) Wn[f] = 0.f;
    if (valid) {
#pragma unroll
      for (int k = 0; k < 9; ++k) {
        float a = sI[dl][b][w + k];
        float bb = sJ[dl][b][w + k];
        if (WITH_I) {
          Wn[0] += a; Wn[1] += a * a;
          Wn[2] += bb; Wn[3] += bb * bb; Wn[4] += a * bb;
        } else {
          Wn[0] += bb; Wn[1] += bb * bb; Wn[2] += a * bb;
        }
      }
    }

#pragma unroll
    for (int f = 0; f < NF; ++f) {
      float old = ring[dl][slot][f][w];
      ring[dl][slot][f][w] = Wn[f];
      S[f] += Wn[f] - old;
    }
    ++slot; if (slot == 9) slot = 0;

    const int ho = hh - 4;
    if (ho >= h0) {
      size_t base = (size_t)d * 16384 + (size_t)ho * 128 + w;
      if (WITH_I) {
        FI[base]                  = (_Float16)S[0];
        FI[(size_t)V3 + base]     = (_Float16)S[1];
        FJ[base]                  = (_Float16)S[2];
        FJ[(size_t)V3 + base]     = (_Float16)S[3];
        FJ[2 * (size_t)V3 + base] = (_Float16)S[4];
      } else {
        FJ[base]                  = (_Float16)S[0];
        FJ[(size_t)V3 + base]     = (_Float16)S[1];
        FJ[2 * (size_t)V3 + base] = (_Float16)S[2];
      }
    }
  }
}

// ---------------- NCC pass 2: flat C=2 windows, 50 independent loads ---------
// Block = 256 = 8h x 16w8 x 2dc. Grid = (16 h-tiles, 32 d-groups of 4, NT).
// Thread computes outputs d0, d0+1 from 10 slices: shared mid-8 + 2 edges.
__global__ __launch_bounds__(256) void n2_kernel(const _Float16* __restrict__ FI,
                                                 const _Float16* __restrict__ FJall,
                                                 float* __restrict__ acc) {
  __shared__ float sm[8];
  const _Float16* FJ = FJall + (size_t)blockIdx.z * 3 * (size_t)V3;
  const int w8 = threadIdx.x & 15;
  const int hl = (threadIdx.x >> 4) & 7;
  const int dc = threadIdx.x >> 7;            // 0..1
  const int h  = blockIdx.x * 8 + hl;
  const int d0 = blockIdx.y * 4 + dc * 2;     // outputs d0, d0+1
  const size_t hw = (size_t)h * 128 + w8 * 8;

  const _Float16* P0 = FI;
  const _Float16* P1 = FI + (size_t)V3;
  const _Float16* P2 = FJ;
  const _Float16* P3 = FJ + (size_t)V3;
  const _Float16* P4 = FJ + 2 * (size_t)V3;

  f8 S0 = {}, S1 = {}, S2 = {}, S3 = {}, S4 = {};
  f8 lo0, lo1, lo2, lo3, lo4, hi0, hi1, hi2, hi3, hi4;

#pragma unroll
  for (int k = 0; k < 10; ++k) {
    const int dd = d0 - 4 + k;
    const bool v = (dd >= 0) && (dd < 128);
    const float m = v ? 1.f : 0.f;
    const size_t a = (size_t)(v ? dd : 0) * 16384 + hw;
    f8 q0 = ldh(P0, a, m);
    f8 q1 = ldh(P1, a, m);
    f8 q2 = ldh(P2, a, m);
    f8 q3 = ldh(P3, a, m);
    f8 q4 = ldh(P4, a, m);
    if (k == 0) {
      lo0 = q0; lo1 = q1; lo2 = q2; lo3 = q3; lo4 = q4;
    } else if (k == 9) {
      hi0 = q0; hi1 = q1; hi2 = q2; hi3 = q3; hi4 = q4;
    } else {
      S0 += q0; S1 += q1; S2 += q2; S3 += q3; S4 += q4;
    }
  }

  const float inv_win = 1.0f / 729.0f;
  float accv = 0.f;
  {
    f8 A0 = S0 + lo0, A1 = S1 + lo1, A2 = S2 + lo2, A3 = S3 + lo3, A4 = S4 + lo4;
    f8 cr = A4 - A0 * A2 * inv_win;
    f8 iv = A1 - A0 * A0 * inv_win;
    f8 jv = A3 - A2 * A2 * inv_win;
    f8 den = iv * jv + 1e-5f;
#pragma unroll
    for (int i = 0; i < 8; ++i)
      accv += cr[i] * cr[i] * __builtin_amdgcn_rcpf(den[i]);
  }
  {
    f8 A0 = S0 + hi0, A1 = S1 + hi1, A2 = S2 + hi2, A3 = S3 + hi3, A4 = S4 + hi4;
    f8 cr = A4 - A0 * A2 * inv_win;
    f8 iv = A1 - A0 * A0 * inv_win;
    f8 jv = A3 - A2 * A2 * inv_win;
    f8 den = iv * jv + 1e-5f;
#pragma unroll
    for (int i = 0; i < 8; ++i)
      accv += cr[i] * cr[i] * __builtin_amdgcn_rcpf(den[i]);
  }

  accv = block_reduce(accv, sm);
  if (threadIdx.x == 0) atomicAdd(acc, accv);
}

// ---------------- final scalar combine ----------------
__global__ void final_kernel(const float* __restrict__ ws,
                             const float* __restrict__ td,
                             float* __restrict__ out) {
  if (threadIdx.x != 0 || blockIdx.x != 0) return;
  float area[4];
  float amax = -1e30f;
#pragma unroll
  for (int t = 0; t < 4; ++t) {
    area[t] = ws[t];
    amax = fmaxf(amax, area[t]);
  }
  float a[4];
#pragma unroll
  for (int t = 0; t < 4; ++t) a[t] = area[t] / amax;

  float sc = 0.f;
  int cnt = 0;
  for (int i = 0; i < 2; ++i)
    for (int j = i + 1; j < 3; ++j)
      for (int k = j + 1; k < 4; ++k) {
        float lam = (td[j] - td[i] + 1e-5f) / (td[k] - td[i] + 1e-5f);
        float e = a[j] - a[i] - lam * (a[k] - a[i]);
        sc += e * e;
        ++cnt;
      }
  sc /= (float)cnt;

  float ncc  = 1.0f - ws[7] / (3.0f * (float)V3);
  float grad = ws[4] / (3.0f * 9.0f * 127.0f * 128.0f * 128.0f);
  out[0] = ncc + 0.1f * grad + 0.1f * sc;
}

extern "C" void kernel_launch(void* const* d_in, const int* in_sizes, int n_in,
                              void* d_out, int out_size, void* d_ws, size_t ws_size,
                              hipStream_t stream) {
  const float* image      = (const float*)d_in[0];
  // d_in[1] = mask (unused by the reference loss)
  const float* pred_image = (const float*)d_in[2];
  const float* pred_mask  = (const float*)d_in[3];
  const float* flow       = (const float*)d_in[4];
  const float* time_diff  = (const float*)d_in[5];
  float* out = (float*)d_out;
  float* wsf = (float*)d_ws;
  _Float16* FI = (_Float16*)(wsf + 64);   // 2 fp16 planes (I_sum, I2_sum)
  _Float16* FJ = FI + 2 * (size_t)V3;     // fp16 J plane-triples

  // zero scalar accumulators: [0..3] area, [4] grad sum, [7] cc sum
  hipMemsetAsync(d_ws, 0, 256, stream);

  hipLaunchKernelGGL(area_kernel, dim3(512, 4), dim3(256), 0, stream,
                     pred_mask, wsf);
  hipLaunchKernelGGL(grad_kernel, dim3(16, 32, 9), dim3(256), 0, stream,
                     flow, wsf + 4);

  const size_t need_fused = 256 + 11 * (size_t)V3 * sizeof(_Float16);
  if (ws_size >= need_fused) {
    // fused path: 9 fp16 J-planes + 2 I-planes live concurrently
    hipLaunchKernelGGL((n1_kernel<true>), dim3(8, 64, 1), dim3(256), 0, stream,
                       image, pred_image + (size_t)V3, FI, FJ);
    hipLaunchKernelGGL((n1_kernel<false>), dim3(8, 64, 2), dim3(256), 0, stream,
                       image, pred_image + 2 * (size_t)V3, FI,
                       FJ + 3 * (size_t)V3);
    hipLaunchKernelGGL(n2_kernel, dim3(16, 32, 3), dim3(256), 0, stream,
                       FI, FJ, wsf + 7);
  } else {
    // sequential path: one J triple reused across t
    for (int t = 0; t < 3; ++t) {
      const float* J = pred_image + (size_t)(t + 1) * V3;
      if (t == 0) {
        hipLaunchKernelGGL((n1_kernel<true>), dim3(8, 64, 1), dim3(256), 0,
                           stream, image, J, FI, FJ);
      } else {
        hipLaunchKernelGGL((n1_kernel<false>), dim3(8, 64, 1), dim3(256), 0,
                           stream, image, J, FI, FJ);
      }
      hipLaunchKernelGGL(n2_kernel, dim3(16, 32, 1), dim3(256), 0, stream,
                         FI, FJ, wsf + 7);
    }
  }

  hipLaunchKernelGGL(final_kernel, dim3(1), dim3(1), 0, stream,
                     wsf, time_diff, out);
}

// Round 11
// 151.531 us; speedup vs baseline: 1.2228x; 1.2228x over previous
//
#include <hip/hip_runtime.h>

#define V3 (128 * 128 * 128)   // 2097152 voxels per volume

typedef _Float16 h8 __attribute__((ext_vector_type(8)));
typedef float    f8 __attribute__((ext_vector_type(8)));

// ---------------- block reduction (wave64) ----------------
__device__ __forceinline__ float block_reduce(float v, float* sm) {
#pragma unroll
  for (int off = 32; off > 0; off >>= 1) v += __shfl_down(v, off, 64);
  int lane = threadIdx.x & 63;
  int wid  = threadIdx.x >> 6;
  if (lane == 0) sm[wid] = v;
  __syncthreads();
  float r = 0.f;
  if ((int)threadIdx.x < (int)(blockDim.x >> 6)) r = sm[threadIdx.x];
  if (wid == 0) {
#pragma unroll
    for (int off = 4; off > 0; off >>= 1) r += __shfl_down(r, off, 64);
  }
  __syncthreads();
  return r;  // valid on thread 0
}

// masked fp16x8 load -> f32x8
__device__ __forceinline__ f8 ldh(const _Float16* __restrict__ p, size_t off,
                                  float m) {
  h8 q = *(const h8*)(p + off);
  f8 r = __builtin_convertvector(q, f8);
  return r * m;
}

// ---------------- pred_mask area sums (per t), float4 ----------------
__global__ __launch_bounds__(256) void area_kernel(const float* __restrict__ pm,
                                                   float* __restrict__ acc) {
  __shared__ float sm[8];
  const int t = blockIdx.y;
  const float* p = pm + (size_t)t * V3;
  const int n4 = V3 / 4;
  float s = 0.f;
  for (int i = blockIdx.x * blockDim.x + threadIdx.x; i < n4;
       i += gridDim.x * blockDim.x) {
    float4 a = *(const float4*)(p + 4 * (size_t)i);
    s += (a.x + a.y) + (a.z + a.w);
  }
  s = block_reduce(s, sm);
  if (threadIdx.x == 0) atomicAdd(acc + t, s);
}

// ---------------- flow gradient: d-walk + shfl h-neighbor for even rows ------
// Block = 256 = 8 h-rows x 32 w4 (wave = rows 2k,2k+1). Grid = (16,16,9).
// Even rows get h+1 from lane+32's cur via shfl; odd rows load it (half-wave).
__global__ __launch_bounds__(256) void grad_kernel(const float* __restrict__ fl,
                                                   float* __restrict__ acc) {
  __shared__ float sm[8];
  const int w4 = threadIdx.x & 31;
  const int hl = threadIdx.x >> 5;           // 0..7
  const int h  = blockIdx.x * 8 + hl;
  const int d0 = blockIdx.y * 8;
  const int c  = blockIdx.z;
  const float* p = fl + (size_t)c * V3 + (size_t)h * 128 + w4 * 4;
  const bool hodd = (hl & 1) != 0;
  const bool hv = (h < 127);                 // false only for hl=7 (odd)

  float s = 0.f;
  float4 cur  = *(const float4*)(p + (size_t)d0 * 16384);
  float4 curh = cur;
  if (hodd && hv) curh = *(const float4*)(p + (size_t)d0 * 16384 + 128);

#pragma unroll
  for (int dd = 0; dd < 8; ++dd) {
    const int d = d0 + dd;
    const bool dv = (d < 127);
    float4 nxt = cur, nxth = curh;
    if (dv) {
      nxt = *(const float4*)(p + (size_t)(d + 1) * 16384);
      if (hodd && hv)
        nxth = *(const float4*)(p + (size_t)(d + 1) * 16384 + 128);
    }
    // w-diffs
    float x;
    x = cur.y - cur.x; s += x * x;
    x = cur.z - cur.y; s += x * x;
    x = cur.w - cur.z; s += x * x;
    const float nx = __shfl_down(cur.x, 1, 64);
    if (w4 != 31) { x = nx - cur.w; s += x * x; }
    // h-diff: even rows pull lane+32's cur (row h+1), odd rows use loaded curh
    float4 hs;
    hs.x = __shfl_down(cur.x, 32, 64);
    hs.y = __shfl_down(cur.y, 32, 64);
    hs.z = __shfl_down(cur.z, 32, 64);
    hs.w = __shfl_down(cur.w, 32, 64);
    const float4 b = hodd ? curh : hs;
    if (hv) {
      x = b.x - cur.x; s += x * x;
      x = b.y - cur.y; s += x * x;
      x = b.z - cur.z; s += x * x;
      x = b.w - cur.w; s += x * x;
    }
    // d-diff
    if (dv) {
      x = nxt.x - cur.x; s += x * x;
      x = nxt.y - cur.y; s += x * x;
      x = nxt.z - cur.z; s += x * x;
      x = nxt.w - cur.w; s += x * x;
    }
    cur = nxt; curh = nxth;
  }
  s = block_reduce(s, sm);
  if (threadIdx.x == 0) atomicAdd(acc, s);
}

// ---------------- NCC pass 1: W+H box sums -> fp16 planes (r6 version) -------
// Block = 256 = 2 d-slices x 128 w. Grid = (8 h-chunks of 16, 64 d-pairs, NT).
template <bool WITH_I>
__global__ __launch_bounds__(256) void n1_kernel(const float* __restrict__ I0,
                                                 const float* __restrict__ Jall,
                                                 _Float16* __restrict__ FI,
                                                 _Float16* __restrict__ FJall) {
  constexpr int NF = WITH_I ? 5 : 3;
  __shared__ float sI[2][2][136];
  __shared__ float sJ[2][2][136];
  __shared__ float ring[2][9][NF][128];

  const int tz = blockIdx.z;
  const float* J = Jall + (size_t)tz * V3;
  _Float16* FJ = FJall + (size_t)tz * 3 * (size_t)V3;

  const int w  = threadIdx.x & 127;
  const int dl = threadIdx.x >> 7;
  const int d  = blockIdx.y * 2 + dl;
  const int h0 = blockIdx.x * 16;
  const float* Ib = I0 + (size_t)d * 16384;
  const float* Jb = J  + (size_t)d * 16384;

  if (w < 4) {
    sI[dl][0][w] = 0.f; sI[dl][1][w] = 0.f;
    sJ[dl][0][w] = 0.f; sJ[dl][1][w] = 0.f;
  }
  if (w >= 124) {
    sI[dl][0][w + 8] = 0.f; sI[dl][1][w + 8] = 0.f;
    sJ[dl][0][w + 8] = 0.f; sJ[dl][1][w + 8] = 0.f;
  }
#pragma unroll
  for (int sl = 0; sl < 9; ++sl)
#pragma unroll
    for (int f = 0; f < NF; ++f) ring[dl][sl][f][w] = 0.f;

  auto stage = [&](int hh) {
    if (hh >= 0 && hh < 128) {
      const int b = hh & 1;
      if (w < 32) {
        float4 v = *(const float4*)(Ib + hh * 128 + w * 4);
        *(float4*)&sI[dl][b][4 + w * 4] = v;
      } else if (w < 64) {
        const int l = w - 32;
        float4 v = *(const float4*)(Jb + hh * 128 + l * 4);
        *(float4*)&sJ[dl][b][4 + l * 4] = v;
      }
    }
  };

  float S[NF];
#pragma unroll
  for (int f = 0; f < NF; ++f) S[f] = 0.f;

  stage(h0 - 4);
  int slot = (h0 + 32) % 9;

  for (int hh = h0 - 4; hh < h0 + 20; ++hh) {
    __syncthreads();
    stage(hh + 1);
    const int b = hh & 1;
    const bool valid = (hh >= 0) && (hh < 128);

    float Wn[NF];
#pragma unroll
    for (int f = 0; f < NF; ++f) Wn[f] = 0.f;
    if (valid) {
#pragma unroll
      for (int k = 0; k < 9; ++k) {
        float a = sI[dl][b][w + k];
        float bb = sJ[dl][b][w + k];
        if (WITH_I) {
          Wn[0] += a; Wn[1] += a * a;
          Wn[2] += bb; Wn[3] += bb * bb; Wn[4] += a * bb;
        } else {
          Wn[0] += bb; Wn[1] += bb * bb; Wn[2] += a * bb;
        }
      }
    }

#pragma unroll
    for (int f = 0; f < NF; ++f) {
      float old = ring[dl][slot][f][w];
      ring[dl][slot][f][w] = Wn[f];
      S[f] += Wn[f] - old;
    }
    ++slot; if (slot == 9) slot = 0;

    const int ho = hh - 4;
    if (ho >= h0) {
      size_t base = (size_t)d * 16384 + (size_t)ho * 128 + w;
      if (WITH_I) {
        FI[base]                  = (_Float16)S[0];
        FI[(size_t)V3 + base]     = (_Float16)S[1];
        FJ[base]                  = (_Float16)S[2];
        FJ[(size_t)V3 + base]     = (_Float16)S[3];
        FJ[2 * (size_t)V3 + base] = (_Float16)S[4];
      } else {
        FJ[base]                  = (_Float16)S[0];
        FJ[(size_t)V3 + base]     = (_Float16)S[1];
        FJ[2 * (size_t)V3 + base] = (_Float16)S[2];
      }
    }
  }
}

// ---------------- NCC pass 2: flat C=2 windows, 50 independent loads ---------
// Block = 256 = 8h x 16w8 x 2dc. Grid = (16 h-tiles, 32 d-groups of 4, NT).
__global__ __launch_bounds__(256) void n2_kernel(const _Float16* __restrict__ FI,
                                                 const _Float16* __restrict__ FJall,
                                                 float* __restrict__ acc) {
  __shared__ float sm[8];
  const _Float16* FJ = FJall + (size_t)blockIdx.z * 3 * (size_t)V3;
  const int w8 = threadIdx.x & 15;
  const int hl = (threadIdx.x >> 4) & 7;
  const int dc = threadIdx.x >> 7;            // 0..1
  const int h  = blockIdx.x * 8 + hl;
  const int d0 = blockIdx.y * 4 + dc * 2;     // outputs d0, d0+1
  const size_t hw = (size_t)h * 128 + w8 * 8;

  const _Float16* P0 = FI;
  const _Float16* P1 = FI + (size_t)V3;
  const _Float16* P2 = FJ;
  const _Float16* P3 = FJ + (size_t)V3;
  const _Float16* P4 = FJ + 2 * (size_t)V3;

  f8 S0 = {}, S1 = {}, S2 = {}, S3 = {}, S4 = {};
  f8 lo0, lo1, lo2, lo3, lo4, hi0, hi1, hi2, hi3, hi4;

#pragma unroll
  for (int k = 0; k < 10; ++k) {
    const int dd = d0 - 4 + k;
    const bool v = (dd >= 0) && (dd < 128);
    const float m = v ? 1.f : 0.f;
    const size_t a = (size_t)(v ? dd : 0) * 16384 + hw;
    f8 q0 = ldh(P0, a, m);
    f8 q1 = ldh(P1, a, m);
    f8 q2 = ldh(P2, a, m);
    f8 q3 = ldh(P3, a, m);
    f8 q4 = ldh(P4, a, m);
    if (k == 0) {
      lo0 = q0; lo1 = q1; lo2 = q2; lo3 = q3; lo4 = q4;
    } else if (k == 9) {
      hi0 = q0; hi1 = q1; hi2 = q2; hi3 = q3; hi4 = q4;
    } else {
      S0 += q0; S1 += q1; S2 += q2; S3 += q3; S4 += q4;
    }
  }

  const float inv_win = 1.0f / 729.0f;
  float accv = 0.f;
  {
    f8 A0 = S0 + lo0, A1 = S1 + lo1, A2 = S2 + lo2, A3 = S3 + lo3, A4 = S4 + lo4;
    f8 cr = A4 - A0 * A2 * inv_win;
    f8 iv = A1 - A0 * A0 * inv_win;
    f8 jv = A3 - A2 * A2 * inv_win;
    f8 den = iv * jv + 1e-5f;
#pragma unroll
    for (int i = 0; i < 8; ++i)
      accv += cr[i] * cr[i] * __builtin_amdgcn_rcpf(den[i]);
  }
  {
    f8 A0 = S0 + hi0, A1 = S1 + hi1, A2 = S2 + hi2, A3 = S3 + hi3, A4 = S4 + hi4;
    f8 cr = A4 - A0 * A2 * inv_win;
    f8 iv = A1 - A0 * A0 * inv_win;
    f8 jv = A3 - A2 * A2 * inv_win;
    f8 den = iv * jv + 1e-5f;
#pragma unroll
    for (int i = 0; i < 8; ++i)
      accv += cr[i] * cr[i] * __builtin_amdgcn_rcpf(den[i]);
  }

  accv = block_reduce(accv, sm);
  if (threadIdx.x == 0) atomicAdd(acc, accv);
}

// ---------------- final scalar combine ----------------
__global__ void final_kernel(const float* __restrict__ ws,
                             const float* __restrict__ td,
                             float* __restrict__ out) {
  if (threadIdx.x != 0 || blockIdx.x != 0) return;
  float area[4];
  float amax = -1e30f;
#pragma unroll
  for (int t = 0; t < 4; ++t) {
    area[t] = ws[t];
    amax = fmaxf(amax, area[t]);
  }
  float a[4];
#pragma unroll
  for (int t = 0; t < 4; ++t) a[t] = area[t] / amax;

  float sc = 0.f;
  int cnt = 0;
  for (int i = 0; i < 2; ++i)
    for (int j = i + 1; j < 3; ++j)
      for (int k = j + 1; k < 4; ++k) {
        float lam = (td[j] - td[i] + 1e-5f) / (td[k] - td[i] + 1e-5f);
        float e = a[j] - a[i] - lam * (a[k] - a[i]);
        sc += e * e;
        ++cnt;
      }
  sc /= (float)cnt;

  float ncc  = 1.0f - ws[7] / (3.0f * (float)V3);
  float grad = ws[4] / (3.0f * 9.0f * 127.0f * 128.0f * 128.0f);
  out[0] = ncc + 0.1f * grad + 0.1f * sc;
}

extern "C" void kernel_launch(void* const* d_in, const int* in_sizes, int n_in,
                              void* d_out, int out_size, void* d_ws, size_t ws_size,
                              hipStream_t stream) {
  const float* image      = (const float*)d_in[0];
  // d_in[1] = mask (unused by the reference loss)
  const float* pred_image = (const float*)d_in[2];
  const float* pred_mask  = (const float*)d_in[3];
  const float* flow       = (const float*)d_in[4];
  const float* time_diff  = (const float*)d_in[5];
  float* out = (float*)d_out;
  float* wsf = (float*)d_ws;
  _Float16* FI = (_Float16*)(wsf + 64);   // 2 fp16 planes (I_sum, I2_sum)
  _Float16* FJ = FI + 2 * (size_t)V3;     // fp16 J plane-triples

  // zero scalar accumulators: [0..3] area, [4] grad sum, [7] cc sum
  hipMemsetAsync(d_ws, 0, 256, stream);

  hipLaunchKernelGGL(area_kernel, dim3(512, 4), dim3(256), 0, stream,
                     pred_mask, wsf);
  hipLaunchKernelGGL(grad_kernel, dim3(16, 16, 9), dim3(256), 0, stream,
                     flow, wsf + 4);

  const size_t need_fused = 256 + 11 * (size_t)V3 * sizeof(_Float16);
  if (ws_size >= need_fused) {
    // fused path: 9 fp16 J-planes + 2 I-planes live concurrently
    hipLaunchKernelGGL((n1_kernel<true>), dim3(8, 64, 1), dim3(256), 0, stream,
                       image, pred_image + (size_t)V3, FI, FJ);
    hipLaunchKernelGGL((n1_kernel<false>), dim3(8, 64, 2), dim3(256), 0, stream,
                       image, pred_image + 2 * (size_t)V3, FI,
                       FJ + 3 * (size_t)V3);
    hipLaunchKernelGGL(n2_kernel, dim3(16, 32, 3), dim3(256), 0, stream,
                       FI, FJ, wsf + 7);
  } else {
    // sequential path: one J triple reused across t
    for (int t = 0; t < 3; ++t) {
      const float* J = pred_image + (size_t)(t + 1) * V3;
      if (t == 0) {
        hipLaunchKernelGGL((n1_kernel<true>), dim3(8, 64, 1), dim3(256), 0,
                           stream, image, J, FI, FJ);
      } else {
        hipLaunchKernelGGL((n1_kernel<false>), dim3(8, 64, 1), dim3(256), 0,
                           stream, image, J, FI, FJ);
      }
      hipLaunchKernelGGL(n2_kernel, dim3(16, 32, 1), dim3(256), 0, stream,
                         FI, FJ, wsf + 7);
    }
  }

  hipLaunchKernelGGL(final_kernel, dim3(1), dim3(1), 0, stream,
                     wsf, time_diff, out);
}

// Round 12
// 140.283 us; speedup vs baseline: 1.3209x; 1.0802x over previous
//
#include <hip/hip_runtime.h>

#define V3 (128 * 128 * 128)   // 2097152 voxels per volume

typedef _Float16 h8 __attribute__((ext_vector_type(8)));
typedef float    f8 __attribute__((ext_vector_type(8)));

// ---------------- block reduction (wave64) ----------------
__device__ __forceinline__ float block_reduce(float v, float* sm) {
#pragma unroll
  for (int off = 32; off > 0; off >>= 1) v += __shfl_down(v, off, 64);
  int lane = threadIdx.x & 63;
  int wid  = threadIdx.x >> 6;
  if (lane == 0) sm[wid] = v;
  __syncthreads();
  float r = 0.f;
  if ((int)threadIdx.x < (int)(blockDim.x >> 6)) r = sm[threadIdx.x];
  if (wid == 0) {
#pragma unroll
    for (int off = 4; off > 0; off >>= 1) r += __shfl_down(r, off, 64);
  }
  __syncthreads();
  return r;  // valid on thread 0
}

// masked fp16x8 load -> f32x8
__device__ __forceinline__ f8 ldh(const _Float16* __restrict__ p, size_t off,
                                  float m) {
  h8 q = *(const h8*)(p + off);
  f8 r = __builtin_convertvector(q, f8);
  return r * m;
}

// ---------------- pred_mask area sums (per t), float4 ----------------
__global__ __launch_bounds__(256) void area_kernel(const float* __restrict__ pm,
                                                   float* __restrict__ acc) {
  __shared__ float sm[8];
  const int t = blockIdx.y;
  const float* p = pm + (size_t)t * V3;
  const int n4 = V3 / 4;
  float s = 0.f;
  for (int i = blockIdx.x * blockDim.x + threadIdx.x; i < n4;
       i += gridDim.x * blockDim.x) {
    float4 a = *(const float4*)(p + 4 * (size_t)i);
    s += (a.x + a.y) + (a.z + a.w);
  }
  s = block_reduce(s, sm);
  if (threadIdx.x == 0) atomicAdd(acc + t, s);
}

// ---------------- flow gradient: LDS-staged slices, each elem loaded once ----
// Block = 256 = 8 h-rows x 32 w4. Grid = (16 h-tiles, 8 d-tiles of 16, 9 c).
// 3-deep LDS slice ring [9 rows][128 w]; d-diff reads the next ring buffer.
__global__ __launch_bounds__(256) void grad_kernel(const float* __restrict__ fl,
                                                   float* __restrict__ acc) {
  __shared__ float sm[8];
  __shared__ float sl[3][9][128];
  const int t  = threadIdx.x;
  const int w4 = t & 31;
  const int hl = t >> 5;        // 0..7
  const int h0 = blockIdx.x * 8;
  const int d0 = blockIdx.y * 16;
  const int c  = blockIdx.z;
  const float* fc = fl + (size_t)c * V3 + (size_t)h0 * 128;
  const bool halo_h = (h0 + 8) < 128;

  auto stage = [&](int buf, int d) {
    if (d < 128) {
      const float* ps = fc + (size_t)d * 16384;
      *(float4*)&sl[buf][hl][w4 * 4] = *(const float4*)(ps + hl * 128 + w4 * 4);
      if (t < 32 && halo_h)
        *(float4*)&sl[buf][8][t * 4] = *(const float4*)(ps + 8 * 128 + t * 4);
    }
  };

  float s = 0.f;
  stage(0, d0);
#pragma unroll
  for (int k = 0; k <= 16; ++k) {
    __syncthreads();                       // slice d0+k ready in sl[k%3]
    if (k < 16) stage((k + 1) % 3, d0 + k + 1);
    if (k >= 1) {
      const int d = d0 + k - 1;
      const float(&A)[9][128] = sl[(k - 1) % 3];
      const float(&B)[9][128] = sl[k % 3];
      const float4 a = *(const float4*)&A[hl][w4 * 4];
      float x;
      x = a.y - a.x; s += x * x;
      x = a.z - a.y; s += x * x;
      x = a.w - a.z; s += x * x;
      if (w4 != 31) { x = A[hl][w4 * 4 + 4] - a.w; s += x * x; }
      if (h0 + hl < 127) {
        const float4 b = *(const float4*)&A[hl + 1][w4 * 4];
        x = b.x - a.x; s += x * x;
        x = b.y - a.y; s += x * x;
        x = b.z - a.z; s += x * x;
        x = b.w - a.w; s += x * x;
      }
      if (d < 127) {
        const float4 bd = *(const float4*)&B[hl][w4 * 4];
        x = bd.x - a.x; s += x * x;
        x = bd.y - a.y; s += x * x;
        x = bd.z - a.z; s += x * x;
        x = bd.w - a.w; s += x * x;
      }
    }
  }
  s = block_reduce(s, sm);
  if (threadIdx.x == 0) atomicAdd(acc, s);
}

// ---------------- NCC pass 1: W+H box sums -> fp16 planes (r6 version) -------
// Block = 256 = 2 d-slices x 128 w. Grid = (8 h-chunks of 16, 64 d-pairs, NT).
template <bool WITH_I>
__global__ __launch_bounds__(256) void n1_kernel(const float* __restrict__ I0,
                                                 const float* __restrict__ Jall,
                                                 _Float16* __restrict__ FI,
                                                 _Float16* __restrict__ FJall) {
  constexpr int NF = WITH_I ? 5 : 3;
  __shared__ float sI[2][2][136];
  __shared__ float sJ[2][2][136];
  __shared__ float ring[2][9][NF][128];

  const int tz = blockIdx.z;
  const float* J = Jall + (size_t)tz * V3;
  _Float16* FJ = FJall + (size_t)tz * 3 * (size_t)V3;

  const int w  = threadIdx.x & 127;
  const int dl = threadIdx.x >> 7;
  const int d  = blockIdx.y * 2 + dl;
  const int h0 = blockIdx.x * 16;
  const float* Ib = I0 + (size_t)d * 16384;
  const float* Jb = J  + (size_t)d * 16384;

  if (w < 4) {
    sI[dl][0][w] = 0.f; sI[dl][1][w] = 0.f;
    sJ[dl][0][w] = 0.f; sJ[dl][1][w] = 0.f;
  }
  if (w >= 124) {
    sI[dl][0][w + 8] = 0.f; sI[dl][1][w + 8] = 0.f;
    sJ[dl][0][w + 8] = 0.f; sJ[dl][1][w + 8] = 0.f;
  }
#pragma unroll
  for (int sl = 0; sl < 9; ++sl)
#pragma unroll
    for (int f = 0; f < NF; ++f) ring[dl][sl][f][w] = 0.f;

  auto stage = [&](int hh) {
    if (hh >= 0 && hh < 128) {
      const int b = hh & 1;
      if (w < 32) {
        float4 v = *(const float4*)(Ib + hh * 128 + w * 4);
        *(float4*)&sI[dl][b][4 + w * 4] = v;
      } else if (w < 64) {
        const int l = w - 32;
        float4 v = *(const float4*)(Jb + hh * 128 + l * 4);
        *(float4*)&sJ[dl][b][4 + l * 4] = v;
      }
    }
  };

  float S[NF];
#pragma unroll
  for (int f = 0; f < NF; ++f) S[f] = 0.f;

  stage(h0 - 4);
  int slot = (h0 + 32) % 9;

  for (int hh = h0 - 4; hh < h0 + 20; ++hh) {
    __syncthreads();
    stage(hh + 1);
    const int b = hh & 1;
    const bool valid = (hh >= 0) && (hh < 128);

    float Wn[NF];
#pragma unroll
    for (int f = 0; f < NF; ++f) Wn[f] = 0.f;
    if (valid) {
#pragma unroll
      for (int k = 0; k < 9; ++k) {
        float a = sI[dl][b][w + k];
        float bb = sJ[dl][b][w + k];
        if (WITH_I) {
          Wn[0] += a; Wn[1] += a * a;
          Wn[2] += bb; Wn[3] += bb * bb; Wn[4] += a * bb;
        } else {
          Wn[0] += bb; Wn[1] += bb * bb; Wn[2] += a * bb;
        }
      }
    }

#pragma unroll
    for (int f = 0; f < NF; ++f) {
      float old = ring[dl][slot][f][w];
      ring[dl][slot][f][w] = Wn[f];
      S[f] += Wn[f] - old;
    }
    ++slot; if (slot == 9) slot = 0;

    const int ho = hh - 4;
    if (ho >= h0) {
      size_t base = (size_t)d * 16384 + (size_t)ho * 128 + w;
      if (WITH_I) {
        FI[base]                  = (_Float16)S[0];
        FI[(size_t)V3 + base]     = (_Float16)S[1];
        FJ[base]                  = (_Float16)S[2];
        FJ[(size_t)V3 + base]     = (_Float16)S[3];
        FJ[2 * (size_t)V3 + base] = (_Float16)S[4];
      } else {
        FJ[base]                  = (_Float16)S[0];
        FJ[(size_t)V3 + base]     = (_Float16)S[1];
        FJ[2 * (size_t)V3 + base] = (_Float16)S[2];
      }
    }
  }
}

// ---------------- NCC pass 2: flat C=2 windows, 50 independent loads ---------
// Block = 256 = 8h x 16w8 x 2dc. Grid = (16 h-tiles, 32 d-groups of 4, NT).
__global__ __launch_bounds__(256) void n2_kernel(const _Float16* __restrict__ FI,
                                                 const _Float16* __restrict__ FJall,
                                                 float* __restrict__ acc) {
  __shared__ float sm[8];
  const _Float16* FJ = FJall + (size_t)blockIdx.z * 3 * (size_t)V3;
  const int w8 = threadIdx.x & 15;
  const int hl = (threadIdx.x >> 4) & 7;
  const int dc = threadIdx.x >> 7;            // 0..1
  const int h  = blockIdx.x * 8 + hl;
  const int d0 = blockIdx.y * 4 + dc * 2;     // outputs d0, d0+1
  const size_t hw = (size_t)h * 128 + w8 * 8;

  const _Float16* P0 = FI;
  const _Float16* P1 = FI + (size_t)V3;
  const _Float16* P2 = FJ;
  const _Float16* P3 = FJ + (size_t)V3;
  const _Float16* P4 = FJ + 2 * (size_t)V3;

  f8 S0 = {}, S1 = {}, S2 = {}, S3 = {}, S4 = {};
  f8 lo0, lo1, lo2, lo3, lo4, hi0, hi1, hi2, hi3, hi4;

#pragma unroll
  for (int k = 0; k < 10; ++k) {
    const int dd = d0 - 4 + k;
    const bool v = (dd >= 0) && (dd < 128);
    const float m = v ? 1.f : 0.f;
    const size_t a = (size_t)(v ? dd : 0) * 16384 + hw;
    f8 q0 = ldh(P0, a, m);
    f8 q1 = ldh(P1, a, m);
    f8 q2 = ldh(P2, a, m);
    f8 q3 = ldh(P3, a, m);
    f8 q4 = ldh(P4, a, m);
    if (k == 0) {
      lo0 = q0; lo1 = q1; lo2 = q2; lo3 = q3; lo4 = q4;
    } else if (k == 9) {
      hi0 = q0; hi1 = q1; hi2 = q2; hi3 = q3; hi4 = q4;
    } else {
      S0 += q0; S1 += q1; S2 += q2; S3 += q3; S4 += q4;
    }
  }

  const float inv_win = 1.0f / 729.0f;
  float accv = 0.f;
  {
    f8 A0 = S0 + lo0, A1 = S1 + lo1, A2 = S2 + lo2, A3 = S3 + lo3, A4 = S4 + lo4;
    f8 cr = A4 - A0 * A2 * inv_win;
    f8 iv = A1 - A0 * A0 * inv_win;
    f8 jv = A3 - A2 * A2 * inv_win;
    f8 den = iv * jv + 1e-5f;
#pragma unroll
    for (int i = 0; i < 8; ++i)
      accv += cr[i] * cr[i] * __builtin_amdgcn_rcpf(den[i]);
  }
  {
    f8 A0 = S0 + hi0, A1 = S1 + hi1, A2 = S2 + hi2, A3 = S3 + hi3, A4 = S4 + hi4;
    f8 cr = A4 - A0 * A2 * inv_win;
    f8 iv = A1 - A0 * A0 * inv_win;
    f8 jv = A3 - A2 * A2 * inv_win;
    f8 den = iv * jv + 1e-5f;
#pragma unroll
    for (int i = 0; i < 8; ++i)
      accv += cr[i] * cr[i] * __builtin_amdgcn_rcpf(den[i]);
  }

  accv = block_reduce(accv, sm);
  if (threadIdx.x == 0) atomicAdd(acc, accv);
}

// ---------------- final scalar combine ----------------
__global__ void final_kernel(const float* __restrict__ ws,
                             const float* __restrict__ td,
                             float* __restrict__ out) {
  if (threadIdx.x != 0 || blockIdx.x != 0) return;
  float area[4];
  float amax = -1e30f;
#pragma unroll
  for (int t = 0; t < 4; ++t) {
    area[t] = ws[t];
    amax = fmaxf(amax, area[t]);
  }
  float a[4];
#pragma unroll
  for (int t = 0; t < 4; ++t) a[t] = area[t] / amax;

  float sc = 0.f;
  int cnt = 0;
  for (int i = 0; i < 2; ++i)
    for (int j = i + 1; j < 3; ++j)
      for (int k = j + 1; k < 4; ++k) {
        float lam = (td[j] - td[i] + 1e-5f) / (td[k] - td[i] + 1e-5f);
        float e = a[j] - a[i] - lam * (a[k] - a[i]);
        sc += e * e;
        ++cnt;
      }
  sc /= (float)cnt;

  float ncc  = 1.0f - ws[7] / (3.0f * (float)V3);
  float grad = ws[4] / (3.0f * 9.0f * 127.0f * 128.0f * 128.0f);
  out[0] = ncc + 0.1f * grad + 0.1f * sc;
}

extern "C" void kernel_launch(void* const* d_in, const int* in_sizes, int n_in,
                              void* d_out, int out_size, void* d_ws, size_t ws_size,
                              hipStream_t stream) {
  const float* image      = (const float*)d_in[0];
  // d_in[1] = mask (unused by the reference loss)
  const float* pred_image = (const float*)d_in[2];
  const float* pred_mask  = (const float*)d_in[3];
  const float* flow       = (const float*)d_in[4];
  const float* time_diff  = (const float*)d_in[5];
  float* out = (float*)d_out;
  float* wsf = (float*)d_ws;
  _Float16* FI = (_Float16*)(wsf + 64);   // 2 fp16 planes (I_sum, I2_sum)
  _Float16* FJ = FI + 2 * (size_t)V3;     // fp16 J plane-triples

  // zero scalar accumulators: [0..3] area, [4] grad sum, [7] cc sum
  hipMemsetAsync(d_ws, 0, 256, stream);

  hipLaunchKernelGGL(area_kernel, dim3(512, 4), dim3(256), 0, stream,
                     pred_mask, wsf);
  hipLaunchKernelGGL(grad_kernel, dim3(16, 8, 9), dim3(256), 0, stream,
                     flow, wsf + 4);

  const size_t need_fused = 256 + 11 * (size_t)V3 * sizeof(_Float16);
  if (ws_size >= need_fused) {
    // fused path: 9 fp16 J-planes + 2 I-planes live concurrently
    hipLaunchKernelGGL((n1_kernel<true>), dim3(8, 64, 1), dim3(256), 0, stream,
                       image, pred_image + (size_t)V3, FI, FJ);
    hipLaunchKernelGGL((n1_kernel<false>), dim3(8, 64, 2), dim3(256), 0, stream,
                       image, pred_image + 2 * (size_t)V3, FI,
                       FJ + 3 * (size_t)V3);
    hipLaunchKernelGGL(n2_kernel, dim3(16, 32, 3), dim3(256), 0, stream,
                       FI, FJ, wsf + 7);
  } else {
    // sequential path: one J triple reused across t
    for (int t = 0; t < 3; ++t) {
      const float* J = pred_image + (size_t)(t + 1) * V3;
      if (t == 0) {
        hipLaunchKernelGGL((n1_kernel<true>), dim3(8, 64, 1), dim3(256), 0,
                           stream, image, J, FI, FJ);
      } else {
        hipLaunchKernelGGL((n1_kernel<false>), dim3(8, 64, 1), dim3(256), 0,
                           stream, image, J, FI, FJ);
      }
      hipLaunchKernelGGL(n2_kernel, dim3(16, 32, 1), dim3(256), 0, stream,
                         FI, FJ, wsf + 7);
    }
  }

  hipLaunchKernelGGL(final_kernel, dim3(1), dim3(1), 0, stream,
                     wsf, time_diff, out);
}

// Round 13
// 138.022 us; speedup vs baseline: 1.3425x; 1.0164x over previous
//
#include <hip/hip_runtime.h>

#define V3 (128 * 128 * 128)   // 2097152 voxels per volume

typedef _Float16 h8 __attribute__((ext_vector_type(8)));
typedef float    f8 __attribute__((ext_vector_type(8)));

// ---------------- block reduction (wave64) ----------------
__device__ __forceinline__ float block_reduce(float v, float* sm) {
#pragma unroll
  for (int off = 32; off > 0; off >>= 1) v += __shfl_down(v, off, 64);
  int lane = threadIdx.x & 63;
  int wid  = threadIdx.x >> 6;
  if (lane == 0) sm[wid] = v;
  __syncthreads();
  float r = 0.f;
  if ((int)threadIdx.x < (int)(blockDim.x >> 6)) r = sm[threadIdx.x];
  if (wid == 0) {
#pragma unroll
    for (int off = 4; off > 0; off >>= 1) r += __shfl_down(r, off, 64);
  }
  __syncthreads();
  return r;  // valid on thread 0
}

// masked fp16x8 load -> f32x8
__device__ __forceinline__ f8 ldh(const _Float16* __restrict__ p, size_t off,
                                  float m) {
  h8 q = *(const h8*)(p + off);
  f8 r = __builtin_convertvector(q, f8);
  return r * m;
}

// ---------------- pred_mask area sums (per t), float4 ----------------
__global__ __launch_bounds__(256) void area_kernel(const float* __restrict__ pm,
                                                   float* __restrict__ acc) {
  __shared__ float sm[8];
  const int t = blockIdx.y;
  const float* p = pm + (size_t)t * V3;
  const int n4 = V3 / 4;
  float s = 0.f;
  for (int i = blockIdx.x * blockDim.x + threadIdx.x; i < n4;
       i += gridDim.x * blockDim.x) {
    float4 a = *(const float4*)(p + 4 * (size_t)i);
    s += (a.x + a.y) + (a.z + a.w);
  }
  s = block_reduce(s, sm);
  if (threadIdx.x == 0) atomicAdd(acc + t, s);
}

// ---------------- flow gradient: row-pair d-walk, requests = unique bytes ----
// Block = 256 = 8 pair-slots x 32 w4; thread owns rows (h0+2*hl, h0+2*hl+1).
// Grid = (8 h-tiles of 16 rows, 16 d-tiles of 8, 9 c) = 4608 waves.
// Odd row's h-neighbor comes from next pair's even row via LDS exchange.
__global__ __launch_bounds__(256) void grad_kernel(const float* __restrict__ fl,
                                                   float* __restrict__ acc) {
  __shared__ float sm[8];
  __shared__ float ex[2][9][128];    // even-row exchange + halo slot 8
  const int t  = threadIdx.x;
  const int w4 = t & 31;
  const int hl = t >> 5;             // 0..7
  const int h0 = blockIdx.x * 16;
  const int d0 = blockIdx.y * 8;
  const int c  = blockIdx.z;
  const int ra = h0 + 2 * hl;        // even row
  const float* pa = fl + (size_t)c * V3 + (size_t)ra * 128 + w4 * 4;
  const float* pb = pa + 128;        // odd row
  const float* ph = fl + (size_t)c * V3 + (size_t)(h0 + 16) * 128;
  const bool halo_v = (h0 + 16) < 128;
  const bool b_hv   = (ra + 1) < 127;   // odd row has an h+1 neighbor

  float4 cur_a = *(const float4*)(pa + (size_t)d0 * 16384);
  float4 cur_b = *(const float4*)(pb + (size_t)d0 * 16384);
  *(float4*)&ex[0][hl][w4 * 4] = cur_a;
  if (t < 32 && halo_v)
    *(float4*)&ex[0][8][t * 4] =
        *(const float4*)(ph + (size_t)d0 * 16384 + t * 4);
  __syncthreads();

  float s = 0.f;
#pragma unroll
  for (int dd = 0; dd < 8; ++dd) {
    const int d = d0 + dd;
    const bool dv = (d < 127);
    const int buf = dd & 1;
    float4 nxt_a = cur_a, nxt_b = cur_b;
    if (dv) {
      nxt_a = *(const float4*)(pa + (size_t)(d + 1) * 16384);
      nxt_b = *(const float4*)(pb + (size_t)(d + 1) * 16384);
    }
    // stage next slice's exchange rows
    *(float4*)&ex[buf ^ 1][hl][w4 * 4] = nxt_a;
    if (t < 32 && halo_v) {
      const int dn = dv ? (d + 1) : d;
      *(float4*)&ex[buf ^ 1][8][t * 4] =
          *(const float4*)(ph + (size_t)dn * 16384 + t * 4);
    }
    // compute on slice d
    const float4 hb = *(const float4*)&ex[buf][hl + 1][w4 * 4];
    float x;
    x = cur_a.y - cur_a.x; s += x * x;
    x = cur_a.z - cur_a.y; s += x * x;
    x = cur_a.w - cur_a.z; s += x * x;
    const float ea = __shfl_down(cur_a.x, 1, 64);
    if (w4 != 31) { x = ea - cur_a.w; s += x * x; }
    x = cur_b.y - cur_b.x; s += x * x;
    x = cur_b.z - cur_b.y; s += x * x;
    x = cur_b.w - cur_b.z; s += x * x;
    const float eb = __shfl_down(cur_b.x, 1, 64);
    if (w4 != 31) { x = eb - cur_b.w; s += x * x; }
    // h-diffs: (b - a) always (a<=126, b<=127); (hb - b) when b<127
    x = cur_b.x - cur_a.x; s += x * x;
    x = cur_b.y - cur_a.y; s += x * x;
    x = cur_b.z - cur_a.z; s += x * x;
    x = cur_b.w - cur_a.w; s += x * x;
    if (b_hv) {
      x = hb.x - cur_b.x; s += x * x;
      x = hb.y - cur_b.y; s += x * x;
      x = hb.z - cur_b.z; s += x * x;
      x = hb.w - cur_b.w; s += x * x;
    }
    if (dv) {
      x = nxt_a.x - cur_a.x; s += x * x;
      x = nxt_a.y - cur_a.y; s += x * x;
      x = nxt_a.z - cur_a.z; s += x * x;
      x = nxt_a.w - cur_a.w; s += x * x;
      x = nxt_b.x - cur_b.x; s += x * x;
      x = nxt_b.y - cur_b.y; s += x * x;
      x = nxt_b.z - cur_b.z; s += x * x;
      x = nxt_b.w - cur_b.w; s += x * x;
    }
    cur_a = nxt_a; cur_b = nxt_b;
    __syncthreads();
  }
  s = block_reduce(s, sm);
  if (t == 0) atomicAdd(acc, s);
}

// ---------------- NCC pass 1: W+H box sums -> fp16 planes (r6 version) -------
// Block = 256 = 2 d-slices x 128 w. Grid = (8 h-chunks of 16, 64 d-pairs, NT).
template <bool WITH_I>
__global__ __launch_bounds__(256) void n1_kernel(const float* __restrict__ I0,
                                                 const float* __restrict__ Jall,
                                                 _Float16* __restrict__ FI,
                                                 _Float16* __restrict__ FJall) {
  constexpr int NF = WITH_I ? 5 : 3;
  __shared__ float sI[2][2][136];
  __shared__ float sJ[2][2][136];
  __shared__ float ring[2][9][NF][128];

  const int tz = blockIdx.z;
  const float* J = Jall + (size_t)tz * V3;
  _Float16* FJ = FJall + (size_t)tz * 3 * (size_t)V3;

  const int w  = threadIdx.x & 127;
  const int dl = threadIdx.x >> 7;
  const int d  = blockIdx.y * 2 + dl;
  const int h0 = blockIdx.x * 16;
  const float* Ib = I0 + (size_t)d * 16384;
  const float* Jb = J  + (size_t)d * 16384;

  if (w < 4) {
    sI[dl][0][w] = 0.f; sI[dl][1][w] = 0.f;
    sJ[dl][0][w] = 0.f; sJ[dl][1][w] = 0.f;
  }
  if (w >= 124) {
    sI[dl][0][w + 8] = 0.f; sI[dl][1][w + 8] = 0.f;
    sJ[dl][0][w + 8] = 0.f; sJ[dl][1][w + 8] = 0.f;
  }
#pragma unroll
  for (int sl = 0; sl < 9; ++sl)
#pragma unroll
    for (int f = 0; f < NF; ++f) ring[dl][sl][f][w] = 0.f;

  auto stage = [&](int hh) {
    if (hh >= 0 && hh < 128) {
      const int b = hh & 1;
      if (w < 32) {
        float4 v = *(const float4*)(Ib + hh * 128 + w * 4);
        *(float4*)&sI[dl][b][4 + w * 4] = v;
      } else if (w < 64) {
        const int l = w - 32;
        float4 v = *(const float4*)(Jb + hh * 128 + l * 4);
        *(float4*)&sJ[dl][b][4 + l * 4] = v;
      }
    }
  };

  float S[NF];
#pragma unroll
  for (int f = 0; f < NF; ++f) S[f] = 0.f;

  stage(h0 - 4);
  int slot = (h0 + 32) % 9;

  for (int hh = h0 - 4; hh < h0 + 20; ++hh) {
    __syncthreads();
    stage(hh + 1);
    const int b = hh & 1;
    const bool valid = (hh >= 0) && (hh < 128);

    float Wn[NF];
#pragma unroll
    for (int f = 0; f < NF; ++f) Wn[f] = 0.f;
    if (valid) {
#pragma unroll
      for (int k = 0; k < 9; ++k) {
        float a = sI[dl][b][w + k];
        float bb = sJ[dl][b][w + k];
        if (WITH_I) {
          Wn[0] += a; Wn[1] += a * a;
          Wn[2] += bb; Wn[3] += bb * bb; Wn[4] += a * bb;
        } else {
          Wn[0] += bb; Wn[1] += bb * bb; Wn[2] += a * bb;
        }
      }
    }

#pragma unroll
    for (int f = 0; f < NF; ++f) {
      float old = ring[dl][slot][f][w];
      ring[dl][slot][f][w] = Wn[f];
      S[f] += Wn[f] - old;
    }
    ++slot; if (slot == 9) slot = 0;

    const int ho = hh - 4;
    if (ho >= h0) {
      size_t base = (size_t)d * 16384 + (size_t)ho * 128 + w;
      if (WITH_I) {
        FI[base]                  = (_Float16)S[0];
        FI[(size_t)V3 + base]     = (_Float16)S[1];
        FJ[base]                  = (_Float16)S[2];
        FJ[(size_t)V3 + base]     = (_Float16)S[3];
        FJ[2 * (size_t)V3 + base] = (_Float16)S[4];
      } else {
        FJ[base]                  = (_Float16)S[0];
        FJ[(size_t)V3 + base]     = (_Float16)S[1];
        FJ[2 * (size_t)V3 + base] = (_Float16)S[2];
      }
    }
  }
}

// ---------------- NCC pass 2: flat C=2 windows, 50 independent loads ---------
// Block = 256 = 8h x 16w8 x 2dc. Grid = (16 h-tiles, 32 d-groups of 4, NT).
__global__ __launch_bounds__(256) void n2_kernel(const _Float16* __restrict__ FI,
                                                 const _Float16* __restrict__ FJall,
                                                 float* __restrict__ acc) {
  __shared__ float sm[8];
  const _Float16* FJ = FJall + (size_t)blockIdx.z * 3 * (size_t)V3;
  const int w8 = threadIdx.x & 15;
  const int hl = (threadIdx.x >> 4) & 7;
  const int dc = threadIdx.x >> 7;            // 0..1
  const int h  = blockIdx.x * 8 + hl;
  const int d0 = blockIdx.y * 4 + dc * 2;     // outputs d0, d0+1
  const size_t hw = (size_t)h * 128 + w8 * 8;

  const _Float16* P0 = FI;
  const _Float16* P1 = FI + (size_t)V3;
  const _Float16* P2 = FJ;
  const _Float16* P3 = FJ + (size_t)V3;
  const _Float16* P4 = FJ + 2 * (size_t)V3;

  f8 S0 = {}, S1 = {}, S2 = {}, S3 = {}, S4 = {};
  f8 lo0, lo1, lo2, lo3, lo4, hi0, hi1, hi2, hi3, hi4;

#pragma unroll
  for (int k = 0; k < 10; ++k) {
    const int dd = d0 - 4 + k;
    const bool v = (dd >= 0) && (dd < 128);
    const float m = v ? 1.f : 0.f;
    const size_t a = (size_t)(v ? dd : 0) * 16384 + hw;
    f8 q0 = ldh(P0, a, m);
    f8 q1 = ldh(P1, a, m);
    f8 q2 = ldh(P2, a, m);
    f8 q3 = ldh(P3, a, m);
    f8 q4 = ldh(P4, a, m);
    if (k == 0) {
      lo0 = q0; lo1 = q1; lo2 = q2; lo3 = q3; lo4 = q4;
    } else if (k == 9) {
      hi0 = q0; hi1 = q1; hi2 = q2; hi3 = q3; hi4 = q4;
    } else {
      S0 += q0; S1 += q1; S2 += q2; S3 += q3; S4 += q4;
    }
  }

  const float inv_win = 1.0f / 729.0f;
  float accv = 0.f;
  {
    f8 A0 = S0 + lo0, A1 = S1 + lo1, A2 = S2 + lo2, A3 = S3 + lo3, A4 = S4 + lo4;
    f8 cr = A4 - A0 * A2 * inv_win;
    f8 iv = A1 - A0 * A0 * inv_win;
    f8 jv = A3 - A2 * A2 * inv_win;
    f8 den = iv * jv + 1e-5f;
#pragma unroll
    for (int i = 0; i < 8; ++i)
      accv += cr[i] * cr[i] * __builtin_amdgcn_rcpf(den[i]);
  }
  {
    f8 A0 = S0 + hi0, A1 = S1 + hi1, A2 = S2 + hi2, A3 = S3 + hi3, A4 = S4 + hi4;
    f8 cr = A4 - A0 * A2 * inv_win;
    f8 iv = A1 - A0 * A0 * inv_win;
    f8 jv = A3 - A2 * A2 * inv_win;
    f8 den = iv * jv + 1e-5f;
#pragma unroll
    for (int i = 0; i < 8; ++i)
      accv += cr[i] * cr[i] * __builtin_amdgcn_rcpf(den[i]);
  }

  accv = block_reduce(accv, sm);
  if (threadIdx.x == 0) atomicAdd(acc, accv);
}

// ---------------- final scalar combine ----------------
__global__ void final_kernel(const float* __restrict__ ws,
                             const float* __restrict__ td,
                             float* __restrict__ out) {
  if (threadIdx.x != 0 || blockIdx.x != 0) return;
  float area[4];
  float amax = -1e30f;
#pragma unroll
  for (int t = 0; t < 4; ++t) {
    area[t] = ws[t];
    amax = fmaxf(amax, area[t]);
  }
  float a[4];
#pragma unroll
  for (int t = 0; t < 4; ++t) a[t] = area[t] / amax;

  float sc = 0.f;
  int cnt = 0;
  for (int i = 0; i < 2; ++i)
    for (int j = i + 1; j < 3; ++j)
      for (int k = j + 1; k < 4; ++k) {
        float lam = (td[j] - td[i] + 1e-5f) / (td[k] - td[i] + 1e-5f);
        float e = a[j] - a[i] - lam * (a[k] - a[i]);
        sc += e * e;
        ++cnt;
      }
  sc /= (float)cnt;

  float ncc  = 1.0f - ws[7] / (3.0f * (float)V3);
  float grad = ws[4] / (3.0f * 9.0f * 127.0f * 128.0f * 128.0f);
  out[0] = ncc + 0.1f * grad + 0.1f * sc;
}

extern "C" void kernel_launch(void* const* d_in, const int* in_sizes, int n_in,
                              void* d_out, int out_size, void* d_ws, size_t ws_size,
                              hipStream_t stream) {
  const float* image      = (const float*)d_in[0];
  // d_in[1] = mask (unused by the reference loss)
  const float* pred_image = (const float*)d_in[2];
  const float* pred_mask  = (const float*)d_in[3];
  const float* flow       = (const float*)d_in[4];
  const float* time_diff  = (const float*)d_in[5];
  float* out = (float*)d_out;
  float* wsf = (float*)d_ws;
  _Float16* FI = (_Float16*)(wsf + 64);   // 2 fp16 planes (I_sum, I2_sum)
  _Float16* FJ = FI + 2 * (size_t)V3;     // fp16 J plane-triples

  // zero scalar accumulators: [0..3] area, [4] grad sum, [7] cc sum
  hipMemsetAsync(d_ws, 0, 256, stream);

  hipLaunchKernelGGL(area_kernel, dim3(512, 4), dim3(256), 0, stream,
                     pred_mask, wsf);
  hipLaunchKernelGGL(grad_kernel, dim3(8, 16, 9), dim3(256), 0, stream,
                     flow, wsf + 4);

  const size_t need_fused = 256 + 11 * (size_t)V3 * sizeof(_Float16);
  if (ws_size >= need_fused) {
    // fused path: 9 fp16 J-planes + 2 I-planes live concurrently
    hipLaunchKernelGGL((n1_kernel<true>), dim3(8, 64, 1), dim3(256), 0, stream,
                       image, pred_image + (size_t)V3, FI, FJ);
    hipLaunchKernelGGL((n1_kernel<false>), dim3(8, 64, 2), dim3(256), 0, stream,
                       image, pred_image + 2 * (size_t)V3, FI,
                       FJ + 3 * (size_t)V3);
    hipLaunchKernelGGL(n2_kernel, dim3(16, 32, 3), dim3(256), 0, stream,
                       FI, FJ, wsf + 7);
  } else {
    // sequential path: one J triple reused across t
    for (int t = 0; t < 3; ++t) {
      const float* J = pred_image + (size_t)(t + 1) * V3;
      if (t == 0) {
        hipLaunchKernelGGL((n1_kernel<true>), dim3(8, 64, 1), dim3(256), 0,
                           stream, image, J, FI, FJ);
      } else {
        hipLaunchKernelGGL((n1_kernel<false>), dim3(8, 64, 1), dim3(256), 0,
                           stream, image, J, FI, FJ);
      }
      hipLaunchKernelGGL(n2_kernel, dim3(16, 32, 1), dim3(256), 0, stream,
                         FI, FJ, wsf + 7);
    }
  }

  hipLaunchKernelGGL(final_kernel, dim3(1), dim3(1), 0, stream,
                     wsf, time_diff, out);
}